// Round 8
// baseline (1297.331 us; speedup 1.0000x reference)
//
#include <hip/hip_runtime.h>
#include <hip/hip_bf16.h>
#include <math.h>

#define N_BATCH 8
#define WDIM 64
#define TDIM 8192
#define KBINS 2048
#define NROWS (N_BATCH * TDIM)          // 65536
#define XSIZE (N_BATCH * WDIM * TDIM)   // 4194304
#define XL_OFF 0
#define XD_OFF NROWS
#define SCAL_OFF (NROWS + XSIZE)

#define MT 64                           // rows per block (vq)
#define XST 72                          // bf16 LDS x row stride
#define TAU 0.05f                       // >=500 sigma of split-bf16 noise
#define MAXFLAG 8192
#define RROWS 16                        // rows per recheck block

// ws layout (bytes):
//   0      : double wsd[4]
//   64     : float  k2[KBINS]          (np-bit-exact)
//   8320   : int    flag_cnt
//   8384   : int    flags[MAXFLAG]     (32 KB)
//   41216  : short  khi[KBINS*64]      (256 KB)
//   303360 : short  klo[KBINS*64]      (256 KB)
#define WS_K2_OFF   64
#define WS_CNT_OFF  8320
#define WS_FLAG_OFF 8384
#define WS_KHI_OFF  41216
#define WS_KLO_OFF  303360

typedef __attribute__((ext_vector_type(8))) short bf16x8;
typedef __attribute__((ext_vector_type(4))) float f32x4;

static __device__ __forceinline__ short f2bf(float v) {
  __hip_bfloat16 b = __float2bfloat16(v);
  return *reinterpret_cast<short*>(&b);
}
static __device__ __forceinline__ float bf2f(short s) {
  unsigned int u = ((unsigned int)(unsigned short)s) << 16;
  return __uint_as_float(u);
}

// prep: init ws + np-bit-exact k2 + split-bf16 codebook, coalesced via LDS.
__global__ void prep_kernel(const float* __restrict__ kg, float* __restrict__ k2,
                            short* __restrict__ khi, short* __restrict__ klo,
                            double* __restrict__ wsd, int* __restrict__ cnt) {
  __shared__ float skc[128 * 65];
  const int tid = threadIdx.x;
  const int c0 = blockIdx.x * 128;
  if (blockIdx.x == 0) {
    if (tid < 4) wsd[tid] = 0.0;
    if (tid == 4) *cnt = 0;
  }
  const float4* g4 = (const float4*)(kg + (size_t)c0 * WDIM);
#pragma unroll
  for (int i = 0; i < 8; ++i) {
    int idx = i * 256 + tid;
    int code = idx >> 4, w = (idx & 15) * 4;
    *(float4*)&skc[code * 65 + w] = g4[idx];
  }
  __syncthreads();
  if (tid < 128) {   // np-bit-exact k2 (8-accumulator pairwise)
    const float* kr = &skc[tid * 65];
    float r[8];
#pragma unroll
    for (int l = 0; l < 8; ++l) r[l] = __fmul_rn(kr[l], kr[l]);
    for (int i = 8; i < WDIM; i += 8) {
#pragma unroll
      for (int l = 0; l < 8; ++l)
        r[l] = __fadd_rn(r[l], __fmul_rn(kr[i + l], kr[i + l]));
    }
    k2[c0 + tid] = __fadd_rn(__fadd_rn(__fadd_rn(r[0], r[1]), __fadd_rn(r[2], r[3])),
                             __fadd_rn(__fadd_rn(r[4], r[5]), __fadd_rn(r[6], r[7])));
  }
#pragma unroll
  for (int i = 0; i < 32; ++i) {
    int idx = i * 256 + tid;
    int code = idx >> 6, w = idx & 63;
    float v = skc[code * 65 + w];
    short h = f2bf(v);
    khi[(size_t)(c0 + code) * WDIM + w] = h;
    klo[(size_t)(c0 + code) * WDIM + w] = f2bf(v - bf2f(h));
  }
}

// main: split-bf16 MFMA scan. 64 rows/block, 2 waves, 32 rows/wave (2 subtiles).
// B-frags (hi+lo) direct from global (L2-resident), depth-1 register prefetch.
__launch_bounds__(128, 2)
__global__ void vq_mfma(const float* __restrict__ x,
                        const float* __restrict__ kg,
                        const float* __restrict__ k2g,
                        const short* __restrict__ khi,
                        const short* __restrict__ klo,
                        float* __restrict__ out,
                        double* __restrict__ wsd,
                        int* __restrict__ flag_cnt,
                        int* __restrict__ flags) {
  __shared__ __align__(16) char smem[19456];
  short* sxh  = (short*)smem;              // [64][72] bf16 hi   (9216 B)
  short* sxl  = (short*)(smem + 9216);     // [64][72] bf16 lo   (9216 B)
  float* sx2  = (float*)(smem + 18432);    // per-row x2         (256 B)
  float* sPair= (float*)(smem + 18688);    // x2 partials        (512 B)
  int*   sIdx = (int*)  (smem + 19200);    // chosen code/row    (256 B)
  float* kd   = (float*)smem;              // epilogue [64][68] f32 (reuses sxh/sxl)

  const int tid  = threadIdx.x;
  const int row0 = blockIdx.x * MT;
  const int n    = row0 >> 13;
  const int t0   = row0 & (TDIM - 1);

  // ---- stage x tile -> split bf16; fp32 partials ----
  const int r  = tid & 63;
  const int wh = tid >> 6;                 // w parity (2 classes)
  float x2p = 0.f, sxp = 0.f;
  const float* xb = x + (size_t)n * WDIM * TDIM + t0 + r;
#pragma unroll 8
  for (int i = 0; i < 32; ++i) {
    int w = 2 * i + wh;
    float v = xb[(size_t)w * TDIM];
    x2p = fmaf(v, v, x2p);
    sxp += v;
    short h = f2bf(v);
    sxh[r * XST + w] = h;
    sxl[r * XST + w] = f2bf(v - bf2f(h));
  }
  sPair[tid] = x2p;
  __syncthreads();
  if (tid < MT) sx2[tid] = sPair[tid] + sPair[tid + 64];
  __syncthreads();

  // ---- A fragments ----
  const int wave = tid >> 6;               // 0/1
  const int lane = tid & 63;
  const int lcol = lane & 15;
  const int quad = lane >> 4;
  const int rA0 = wave * 32 + lcol;
  const int rA1 = wave * 32 + 16 + lcol;
  bf16x8 a0h0 = *(const bf16x8*)&sxh[rA0 * XST + 0  + quad * 8];
  bf16x8 a0h1 = *(const bf16x8*)&sxh[rA0 * XST + 32 + quad * 8];
  bf16x8 a0l0 = *(const bf16x8*)&sxl[rA0 * XST + 0  + quad * 8];
  bf16x8 a0l1 = *(const bf16x8*)&sxl[rA0 * XST + 32 + quad * 8];
  bf16x8 a1h0 = *(const bf16x8*)&sxh[rA1 * XST + 0  + quad * 8];
  bf16x8 a1h1 = *(const bf16x8*)&sxh[rA1 * XST + 32 + quad * 8];
  bf16x8 a1l0 = *(const bf16x8*)&sxl[rA1 * XST + 0  + quad * 8];
  bf16x8 a1l1 = *(const bf16x8*)&sxl[rA1 * XST + 32 + quad * 8];

  float bd[8], b2[8];
  int   bi[8];
#pragma unroll
  for (int i = 0; i < 8; ++i) { bd[i] = 3.0e38f; b2[i] = 3.0e38f; bi[i] = 0; }

  const short* kbh = khi + (size_t)(lcol * WDIM + quad * 8);
  const short* kbl = klo + (size_t)(lcol * WDIM + quad * 8);
  const float* k2b = k2g + lcol;

  bf16x8 ph0, ph1, pl0, pl1, qh0, qh1, ql0, ql1;
  float  pk2, qk2;
  ph0 = *(const bf16x8*)&kbh[0];
  ph1 = *(const bf16x8*)&kbh[32];
  pl0 = *(const bf16x8*)&kbl[0];
  pl1 = *(const bf16x8*)&kbl[32];
  pk2 = k2b[0];

#define VQ_STEP(BH0, BH1, BL0, BL1, KK, CB)                                  \
  {                                                                          \
    f32x4 acc0 = {0.f, 0.f, 0.f, 0.f};                                       \
    f32x4 acc1 = {0.f, 0.f, 0.f, 0.f};                                       \
    acc0 = __builtin_amdgcn_mfma_f32_16x16x32_bf16(a0h0, BH0, acc0, 0, 0, 0);\
    acc1 = __builtin_amdgcn_mfma_f32_16x16x32_bf16(a1h0, BH0, acc1, 0, 0, 0);\
    acc0 = __builtin_amdgcn_mfma_f32_16x16x32_bf16(a0h1, BH1, acc0, 0, 0, 0);\
    acc1 = __builtin_amdgcn_mfma_f32_16x16x32_bf16(a1h1, BH1, acc1, 0, 0, 0);\
    acc0 = __builtin_amdgcn_mfma_f32_16x16x32_bf16(a0h0, BL0, acc0, 0, 0, 0);\
    acc1 = __builtin_amdgcn_mfma_f32_16x16x32_bf16(a1h0, BL0, acc1, 0, 0, 0);\
    acc0 = __builtin_amdgcn_mfma_f32_16x16x32_bf16(a0h1, BL1, acc0, 0, 0, 0);\
    acc1 = __builtin_amdgcn_mfma_f32_16x16x32_bf16(a1h1, BL1, acc1, 0, 0, 0);\
    acc0 = __builtin_amdgcn_mfma_f32_16x16x32_bf16(a0l0, BH0, acc0, 0, 0, 0);\
    acc1 = __builtin_amdgcn_mfma_f32_16x16x32_bf16(a1l0, BH0, acc1, 0, 0, 0);\
    acc0 = __builtin_amdgcn_mfma_f32_16x16x32_bf16(a0l1, BH1, acc0, 0, 0, 0);\
    acc1 = __builtin_amdgcn_mfma_f32_16x16x32_bf16(a1l1, BH1, acc1, 0, 0, 0);\
    const int code = (CB) + lcol;                                            \
    _Pragma("unroll")                                                        \
    for (int i = 0; i < 4; ++i) {                                            \
      float d0 = fmaf(-2.f, acc0[i], KK);                                    \
      float nb2a = fminf(b2[i], fmaxf(bd[i], d0));                           \
      bool lt0 = d0 < bd[i];                                                 \
      bd[i] = lt0 ? d0 : bd[i];                                              \
      bi[i] = lt0 ? code : bi[i];                                            \
      b2[i] = nb2a;                                                          \
      float d1 = fmaf(-2.f, acc1[i], KK);                                    \
      float nb2b = fminf(b2[4 + i], fmaxf(bd[4 + i], d1));                   \
      bool lt1 = d1 < bd[4 + i];                                             \
      bd[4 + i] = lt1 ? d1 : bd[4 + i];                                      \
      bi[4 + i] = lt1 ? code : bi[4 + i];                                    \
      b2[4 + i] = nb2b;                                                      \
    }                                                                        \
  }

  for (int cb = 0; cb < KBINS; cb += 32) {
    {
      const short* ph = kbh + (size_t)(cb + 16) * WDIM;
      const short* pl = kbl + (size_t)(cb + 16) * WDIM;
      qh0 = *(const bf16x8*)&ph[0];
      qh1 = *(const bf16x8*)&ph[32];
      ql0 = *(const bf16x8*)&pl[0];
      ql1 = *(const bf16x8*)&pl[32];
      qk2 = k2b[cb + 16];
    }
    VQ_STEP(ph0, ph1, pl0, pl1, pk2, cb)
    {
      const int nxt = (cb + 32) & (KBINS - 1);   // wraps to 0 on last iter
      const short* ph = kbh + (size_t)nxt * WDIM;
      const short* pl = kbl + (size_t)nxt * WDIM;
      ph0 = *(const bf16x8*)&ph[0];
      ph1 = *(const bf16x8*)&ph[32];
      pl0 = *(const bf16x8*)&pl[0];
      pl1 = *(const bf16x8*)&pl[32];
      pk2 = k2b[nxt];
    }
    VQ_STEP(qh0, qh1, ql0, ql1, qk2, cb + 16)
  }
#undef VQ_STEP

  // ---- reduce across the 16 col-classes ----
#pragma unroll
  for (int m = 1; m < 16; m <<= 1) {
#pragma unroll
    for (int i = 0; i < 8; ++i) {
      float od  = __shfl_xor(bd[i], m, 64);
      float od2 = __shfl_xor(b2[i], m, 64);
      int   oi  = __shfl_xor(bi[i], m, 64);
      float nb2 = fminf(fminf(b2[i], od2), fmaxf(bd[i], od));
      bool take = (od < bd[i]) || (od == bd[i] && oi < bi[i]);
      bd[i] = take ? od : bd[i];
      bi[i] = take ? oi : bi[i];
      b2[i] = nb2;
    }
  }

  float fit_p = 0.f;
  if (lcol == 0) {
#pragma unroll
    for (int i = 0; i < 8; ++i) {
      int s = i >> 2, ii = i & 3;
      int rloc = wave * 32 + s * 16 + quad * 4 + ii;
      int rowg = row0 + rloc;
      out[XL_OFF + rowg] = (float)bi[i];
      sIdx[rloc] = bi[i];
      fit_p += bd[i] + sx2[rloc];
      if (b2[i] - bd[i] < TAU) {
        int slot = atomicAdd(flag_cnt, 1);
        if (slot < MAXFLAG) flags[slot] = rowg;
      }
    }
  }
  __syncthreads();

  // ---- gather chosen code rows (fp32) into LDS ----
  {
    int rr = tid >> 1, half = tid & 1;
    const float4* kr4 = (const float4*)(kg + (size_t)sIdx[rr] * WDIM + half * 32);
    float4* dst = (float4*)&kd[rr * 68 + half * 32];
#pragma unroll
    for (int j = 0; j < 8; ++j) dst[j] = kr4[j];
  }
  __syncthreads();

  // ---- x_d transposed write + commit ----
  float commit_p = 0.f;
  float* xdb = out + XD_OFF + (size_t)n * WDIM * TDIM + t0 + r;
#pragma unroll 8
  for (int i = 0; i < 32; ++i) {
    int w = 2 * i + wh;
    float xvv = xb[(size_t)w * TDIM];
    float kvv = kd[r * 68 + w];
    float df = kvv - xvv;
    commit_p = fmaf(df, df, commit_p);
    xdb[(size_t)w * TDIM] = kvv;
  }

  // ---- scalar reduction -> global atomics ----
  float v0 = sxp, v1 = x2p, v2 = commit_p, v3 = fit_p;
#pragma unroll
  for (int off = 32; off > 0; off >>= 1) {
    v0 += __shfl_down(v0, off, 64);
    v1 += __shfl_down(v1, off, 64);
    v2 += __shfl_down(v2, off, 64);
    v3 += __shfl_down(v3, off, 64);
  }
  if (lane == 0) {
    atomicAdd(&wsd[0], (double)v0);
    atomicAdd(&wsd[1], (double)v1);
    atomicAdd(&wsd[2], (double)v2);
    atomicAdd(&wsd[3], (double)v3);
  }
}

// numpy-bit-exact fp32 re-scan: 16 flagged rows per block, codebook read once.
__launch_bounds__(256, 4)
__global__ void recheck_np(const float* __restrict__ x,
                           const float* __restrict__ kg,
                           const float* __restrict__ k2g,
                           const int* __restrict__ flag_cnt,
                           const int* __restrict__ flags,
                           float* __restrict__ out) {
  __shared__ float sxr[RROWS][WDIM];
  __shared__ float sx2r[RROWS];
  __shared__ int   srow[RROWS];
  __shared__ float sWd[4 * RROWS];
  __shared__ int   sWi[4 * RROWS];
  __shared__ int   swin[RROWS];

  const int tid = threadIdx.x;
  int nf = *flag_cnt;
  if (nf > MAXFLAG) nf = MAXFLAG;
  const int base = blockIdx.x * RROWS;
  if (base >= nf) return;
  const int m = (nf - base < RROWS) ? (nf - base) : RROWS;

  if (tid < RROWS) srow[tid] = (tid < m) ? flags[base + tid] : 0;
  __syncthreads();

#pragma unroll
  for (int p = 0; p < 4; ++p) {
    int l = p * 4 + (tid >> 6);
    int w = tid & 63;
    if (l < m) {
      int row = srow[l];
      int n2 = row >> 13, t2 = row & (TDIM - 1);
      sxr[l][w] = x[(size_t)n2 * WDIM * TDIM + (size_t)w * TDIM + t2];
    } else {
      sxr[l][w] = 0.f;
    }
  }
  __syncthreads();

  if (tid < RROWS) {   // np-pairwise x2 per row
    const float* sxx = sxr[tid];
    float r8[8];
#pragma unroll
    for (int l = 0; l < 8; ++l) r8[l] = __fmul_rn(sxx[l], sxx[l]);
    for (int i = 8; i < WDIM; i += 8) {
#pragma unroll
      for (int l = 0; l < 8; ++l)
        r8[l] = __fadd_rn(r8[l], __fmul_rn(sxx[i + l], sxx[i + l]));
    }
    sx2r[tid] = __fadd_rn(__fadd_rn(__fadd_rn(r8[0], r8[1]), __fadd_rn(r8[2], r8[3])),
                          __fadd_rn(__fadd_rn(r8[4], r8[5]), __fadd_rn(r8[6], r8[7])));
  }
  __syncthreads();

  float bdv[RROWS];
  int   biv[RROWS];
#pragma unroll
  for (int i = 0; i < RROWS; ++i) { bdv[i] = 3.4e38f; biv[i] = KBINS; }

  for (int c = 0; c < KBINS / 256; ++c) {   // 8 chunks; per-thread j ascending
    const int j = c * 256 + tid;
    const float* kr = kg + (size_t)j * WDIM;
    float acc[RROWS];
#pragma unroll
    for (int i = 0; i < RROWS; ++i) acc[i] = 0.f;
#pragma unroll
    for (int w = 0; w < WDIM; ++w) {
      float kv = kr[w];
#pragma unroll
      for (int i = 0; i < RROWS; ++i)
        acc[i] = __fmaf_rn(sxr[i][w], kv, acc[i]);
    }
    float k2v = k2g[j];
#pragma unroll
    for (int i = 0; i < RROWS; ++i) {
      float d = __fadd_rn(__fsub_rn(sx2r[i], __fmul_rn(2.0f, acc[i])), k2v);
      if (d < bdv[i]) { bdv[i] = d; biv[i] = j; }
    }
  }

  // per-row argmin: wave shuffle reduce, then cross-wave merge
  const int wv = tid >> 6;
#pragma unroll
  for (int l = 0; l < RROWS; ++l) {
    float d = bdv[l];
    int   ii = biv[l];
#pragma unroll
    for (int off = 32; off > 0; off >>= 1) {
      float od = __shfl_down(d, off, 64);
      int   oi = __shfl_down(ii, off, 64);
      if (od < d || (od == d && oi < ii)) { d = od; ii = oi; }
    }
    if ((tid & 63) == 0) { sWd[wv * RROWS + l] = d; sWi[wv * RROWS + l] = ii; }
  }
  __syncthreads();
  if (tid < RROWS) {
    float bw = sWd[tid]; int bwi = sWi[tid];
#pragma unroll
    for (int q = 1; q < 4; ++q) {
      float od = sWd[q * RROWS + tid];
      int   oi = sWi[q * RROWS + tid];
      if (od < bw || (od == bw && oi < bwi)) { bw = od; bwi = oi; }
    }
    swin[tid] = bwi;
    if (tid < m) out[XL_OFF + srow[tid]] = (float)bwi;
  }
  __syncthreads();

#pragma unroll
  for (int p = 0; p < 4; ++p) {
    int l = p * 4 + (tid >> 6);
    int w = tid & 63;
    if (l < m) {
      int row = srow[l];
      int n2 = row >> 13, t2 = row & (TDIM - 1);
      out[XD_OFF + (size_t)n2 * WDIM * TDIM + (size_t)w * TDIM + t2] =
          kg[(size_t)swin[l] * WDIM + w];
    }
  }
}

__global__ void finalize_kernel(const double* __restrict__ wsd, float* __restrict__ out) {
  if (threadIdx.x == 0) {
    double size = (double)XSIZE;
    double commit = wsd[2] / size;
    double fit = wsd[3] / (double)NROWS;
    double mean = wsd[0] / size;
    double var = wsd[1] / size - mean * mean;
    if (var < 0.0) var = 0.0;
    out[SCAL_OFF + 0] = (float)commit;
    out[SCAL_OFF + 1] = (float)fit;
    out[SCAL_OFF + 2] = (float)sqrt(var);
  }
}

extern "C" void kernel_launch(void* const* d_in, const int* in_sizes, int n_in,
                              void* d_out, int out_size, void* d_ws, size_t ws_size,
                              hipStream_t stream) {
  const float* x = (const float*)d_in[0];
  const float* kg = (const float*)d_in[1];
  float* out = (float*)d_out;
  double* wsd = (double*)d_ws;
  float* k2  = (float*)((char*)d_ws + WS_K2_OFF);
  int* cnt   = (int*)((char*)d_ws + WS_CNT_OFF);
  int* flags = (int*)((char*)d_ws + WS_FLAG_OFF);
  short* khi = (short*)((char*)d_ws + WS_KHI_OFF);
  short* klo = (short*)((char*)d_ws + WS_KLO_OFF);

  hipLaunchKernelGGL(prep_kernel, dim3(KBINS / 128), dim3(256), 0, stream,
                     kg, k2, khi, klo, wsd, cnt);
  hipLaunchKernelGGL(vq_mfma, dim3(NROWS / MT), dim3(128), 0, stream,
                     x, kg, k2, khi, klo, out, wsd, cnt, flags);
  hipLaunchKernelGGL(recheck_np, dim3(MAXFLAG / RROWS), dim3(256), 0, stream,
                     x, kg, k2, cnt, flags, out);
  hipLaunchKernelGGL(finalize_kernel, dim3(1), dim3(1), 0, stream, wsd, out);
}

// Round 9
// 353.611 us; speedup vs baseline: 3.6688x; 3.6688x over previous
//
#include <hip/hip_runtime.h>
#include <hip/hip_bf16.h>
#include <math.h>

#define N_BATCH 8
#define WDIM 64
#define TDIM 8192
#define KBINS 2048
#define NROWS (N_BATCH * TDIM)          // 65536
#define XSIZE (N_BATCH * WDIM * TDIM)   // 4194304
#define XL_OFF 0
#define XD_OFF NROWS
#define SCAL_OFF (NROWS + XSIZE)

#define MT 64                           // rows per block (vq)
#define XST 72                          // bf16 LDS x row stride
#define TAU 0.05f                       // >=16x worst-case split-bf16 vs np noise
#define MAXFLAG 8192

// ws layout (bytes):
//   0      : double wsd[4]
//   64     : float  k2[KBINS]              (np-bit-exact)
//   8320   : int    flag_cnt
//   8384   : int    flags[MAXFLAG]         (32 KB)
//   41216  : u64    slots[MAXFLAG]         (64 KB, packed (dist_bits<<32)|idx)
//   106752 : short  khi[KBINS*64]          (256 KB)
//   368896 : short  klo[KBINS*64]          (256 KB)
#define WS_K2_OFF   64
#define WS_CNT_OFF  8320
#define WS_FLAG_OFF 8384
#define WS_SLOT_OFF 41216
#define WS_KHI_OFF  106752
#define WS_KLO_OFF  368896

typedef __attribute__((ext_vector_type(8))) short bf16x8;
typedef __attribute__((ext_vector_type(4))) float f32x4;
typedef unsigned long long u64;

static __device__ __forceinline__ short f2bf(float v) {
  __hip_bfloat16 b = __float2bfloat16(v);
  return *reinterpret_cast<short*>(&b);
}
static __device__ __forceinline__ float bf2f(short s) {
  unsigned int u = ((unsigned int)(unsigned short)s) << 16;
  return __uint_as_float(u);
}

// prep: init ws (wsd, cnt, slots) + np-bit-exact k2 + split-bf16 codebook.
__global__ void prep_kernel(const float* __restrict__ kg, float* __restrict__ k2,
                            short* __restrict__ khi, short* __restrict__ klo,
                            double* __restrict__ wsd, int* __restrict__ cnt,
                            u64* __restrict__ slots) {
  __shared__ float skc[128 * 65];
  const int tid = threadIdx.x;
  const int c0 = blockIdx.x * 128;
  if (blockIdx.x == 0) {
    if (tid < 4) wsd[tid] = 0.0;
    if (tid == 4) *cnt = 0;
  }
  {
    int gid = blockIdx.x * 256 + tid;          // 4096 threads, 8192 slots
    slots[gid] = ~0ULL;
    slots[gid + 4096] = ~0ULL;
  }
  const float4* g4 = (const float4*)(kg + (size_t)c0 * WDIM);
#pragma unroll
  for (int i = 0; i < 8; ++i) {
    int idx = i * 256 + tid;
    int code = idx >> 4, w = (idx & 15) * 4;
    *(float4*)&skc[code * 65 + w] = g4[idx];
  }
  __syncthreads();
  if (tid < 128) {   // np-bit-exact k2 (8-accumulator pairwise)
    const float* kr = &skc[tid * 65];
    float r[8];
#pragma unroll
    for (int l = 0; l < 8; ++l) r[l] = __fmul_rn(kr[l], kr[l]);
    for (int i = 8; i < WDIM; i += 8) {
#pragma unroll
      for (int l = 0; l < 8; ++l)
        r[l] = __fadd_rn(r[l], __fmul_rn(kr[i + l], kr[i + l]));
    }
    k2[c0 + tid] = __fadd_rn(__fadd_rn(__fadd_rn(r[0], r[1]), __fadd_rn(r[2], r[3])),
                             __fadd_rn(__fadd_rn(r[4], r[5]), __fadd_rn(r[6], r[7])));
  }
#pragma unroll
  for (int i = 0; i < 32; ++i) {
    int idx = i * 256 + tid;
    int code = idx >> 6, w = idx & 63;
    float v = skc[code * 65 + w];
    short h = f2bf(v);
    khi[(size_t)(c0 + code) * WDIM + w] = h;
    klo[(size_t)(c0 + code) * WDIM + w] = f2bf(v - bf2f(h));
  }
}

// main: split-bf16 MFMA scan (identical to round 8 — passed validation).
__launch_bounds__(128, 2)
__global__ void vq_mfma(const float* __restrict__ x,
                        const float* __restrict__ kg,
                        const float* __restrict__ k2g,
                        const short* __restrict__ khi,
                        const short* __restrict__ klo,
                        float* __restrict__ out,
                        double* __restrict__ wsd,
                        int* __restrict__ flag_cnt,
                        int* __restrict__ flags) {
  __shared__ __align__(16) char smem[19456];
  short* sxh  = (short*)smem;              // [64][72] bf16 hi   (9216 B)
  short* sxl  = (short*)(smem + 9216);     // [64][72] bf16 lo   (9216 B)
  float* sx2  = (float*)(smem + 18432);    // per-row x2         (256 B)
  float* sPair= (float*)(smem + 18688);    // x2 partials        (512 B)
  int*   sIdx = (int*)  (smem + 19200);    // chosen code/row    (256 B)
  float* kd   = (float*)smem;              // epilogue [64][68] f32 (reuses sxh/sxl)

  const int tid  = threadIdx.x;
  const int row0 = blockIdx.x * MT;
  const int n    = row0 >> 13;
  const int t0   = row0 & (TDIM - 1);

  const int r  = tid & 63;
  const int wh = tid >> 6;
  float x2p = 0.f, sxp = 0.f;
  const float* xb = x + (size_t)n * WDIM * TDIM + t0 + r;
#pragma unroll 8
  for (int i = 0; i < 32; ++i) {
    int w = 2 * i + wh;
    float v = xb[(size_t)w * TDIM];
    x2p = fmaf(v, v, x2p);
    sxp += v;
    short h = f2bf(v);
    sxh[r * XST + w] = h;
    sxl[r * XST + w] = f2bf(v - bf2f(h));
  }
  sPair[tid] = x2p;
  __syncthreads();
  if (tid < MT) sx2[tid] = sPair[tid] + sPair[tid + 64];
  __syncthreads();

  const int wave = tid >> 6;
  const int lane = tid & 63;
  const int lcol = lane & 15;
  const int quad = lane >> 4;
  const int rA0 = wave * 32 + lcol;
  const int rA1 = wave * 32 + 16 + lcol;
  bf16x8 a0h0 = *(const bf16x8*)&sxh[rA0 * XST + 0  + quad * 8];
  bf16x8 a0h1 = *(const bf16x8*)&sxh[rA0 * XST + 32 + quad * 8];
  bf16x8 a0l0 = *(const bf16x8*)&sxl[rA0 * XST + 0  + quad * 8];
  bf16x8 a0l1 = *(const bf16x8*)&sxl[rA0 * XST + 32 + quad * 8];
  bf16x8 a1h0 = *(const bf16x8*)&sxh[rA1 * XST + 0  + quad * 8];
  bf16x8 a1h1 = *(const bf16x8*)&sxh[rA1 * XST + 32 + quad * 8];
  bf16x8 a1l0 = *(const bf16x8*)&sxl[rA1 * XST + 0  + quad * 8];
  bf16x8 a1l1 = *(const bf16x8*)&sxl[rA1 * XST + 32 + quad * 8];

  float bd[8], b2[8];
  int   bi[8];
#pragma unroll
  for (int i = 0; i < 8; ++i) { bd[i] = 3.0e38f; b2[i] = 3.0e38f; bi[i] = 0; }

  const short* kbh = khi + (size_t)(lcol * WDIM + quad * 8);
  const short* kbl = klo + (size_t)(lcol * WDIM + quad * 8);
  const float* k2b = k2g + lcol;

  bf16x8 ph0, ph1, pl0, pl1, qh0, qh1, ql0, ql1;
  float  pk2, qk2;
  ph0 = *(const bf16x8*)&kbh[0];
  ph1 = *(const bf16x8*)&kbh[32];
  pl0 = *(const bf16x8*)&kbl[0];
  pl1 = *(const bf16x8*)&kbl[32];
  pk2 = k2b[0];

#define VQ_STEP(BH0, BH1, BL0, BL1, KK, CB)                                  \
  {                                                                          \
    f32x4 acc0 = {0.f, 0.f, 0.f, 0.f};                                       \
    f32x4 acc1 = {0.f, 0.f, 0.f, 0.f};                                       \
    acc0 = __builtin_amdgcn_mfma_f32_16x16x32_bf16(a0h0, BH0, acc0, 0, 0, 0);\
    acc1 = __builtin_amdgcn_mfma_f32_16x16x32_bf16(a1h0, BH0, acc1, 0, 0, 0);\
    acc0 = __builtin_amdgcn_mfma_f32_16x16x32_bf16(a0h1, BH1, acc0, 0, 0, 0);\
    acc1 = __builtin_amdgcn_mfma_f32_16x16x32_bf16(a1h1, BH1, acc1, 0, 0, 0);\
    acc0 = __builtin_amdgcn_mfma_f32_16x16x32_bf16(a0h0, BL0, acc0, 0, 0, 0);\
    acc1 = __builtin_amdgcn_mfma_f32_16x16x32_bf16(a1h0, BL0, acc1, 0, 0, 0);\
    acc0 = __builtin_amdgcn_mfma_f32_16x16x32_bf16(a0h1, BL1, acc0, 0, 0, 0);\
    acc1 = __builtin_amdgcn_mfma_f32_16x16x32_bf16(a1h1, BL1, acc1, 0, 0, 0);\
    acc0 = __builtin_amdgcn_mfma_f32_16x16x32_bf16(a0l0, BH0, acc0, 0, 0, 0);\
    acc1 = __builtin_amdgcn_mfma_f32_16x16x32_bf16(a1l0, BH0, acc1, 0, 0, 0);\
    acc0 = __builtin_amdgcn_mfma_f32_16x16x32_bf16(a0l1, BH1, acc0, 0, 0, 0);\
    acc1 = __builtin_amdgcn_mfma_f32_16x16x32_bf16(a1l1, BH1, acc1, 0, 0, 0);\
    const int code = (CB) + lcol;                                            \
    _Pragma("unroll")                                                        \
    for (int i = 0; i < 4; ++i) {                                            \
      float d0 = fmaf(-2.f, acc0[i], KK);                                    \
      float nb2a = fminf(b2[i], fmaxf(bd[i], d0));                           \
      bool lt0 = d0 < bd[i];                                                 \
      bd[i] = lt0 ? d0 : bd[i];                                              \
      bi[i] = lt0 ? code : bi[i];                                            \
      b2[i] = nb2a;                                                          \
      float d1 = fmaf(-2.f, acc1[i], KK);                                    \
      float nb2b = fminf(b2[4 + i], fmaxf(bd[4 + i], d1));                   \
      bool lt1 = d1 < bd[4 + i];                                             \
      bd[4 + i] = lt1 ? d1 : bd[4 + i];                                      \
      bi[4 + i] = lt1 ? code : bi[4 + i];                                    \
      b2[4 + i] = nb2b;                                                      \
    }                                                                        \
  }

  for (int cb = 0; cb < KBINS; cb += 32) {
    {
      const short* ph = kbh + (size_t)(cb + 16) * WDIM;
      const short* pl = kbl + (size_t)(cb + 16) * WDIM;
      qh0 = *(const bf16x8*)&ph[0];
      qh1 = *(const bf16x8*)&ph[32];
      ql0 = *(const bf16x8*)&pl[0];
      ql1 = *(const bf16x8*)&pl[32];
      qk2 = k2b[cb + 16];
    }
    VQ_STEP(ph0, ph1, pl0, pl1, pk2, cb)
    {
      const int nxt = (cb + 32) & (KBINS - 1);
      const short* ph = kbh + (size_t)nxt * WDIM;
      const short* pl = kbl + (size_t)nxt * WDIM;
      ph0 = *(const bf16x8*)&ph[0];
      ph1 = *(const bf16x8*)&ph[32];
      pl0 = *(const bf16x8*)&pl[0];
      pl1 = *(const bf16x8*)&pl[32];
      pk2 = k2b[nxt];
    }
    VQ_STEP(qh0, qh1, ql0, ql1, qk2, cb + 16)
  }
#undef VQ_STEP

#pragma unroll
  for (int m = 1; m < 16; m <<= 1) {
#pragma unroll
    for (int i = 0; i < 8; ++i) {
      float od  = __shfl_xor(bd[i], m, 64);
      float od2 = __shfl_xor(b2[i], m, 64);
      int   oi  = __shfl_xor(bi[i], m, 64);
      float nb2 = fminf(fminf(b2[i], od2), fmaxf(bd[i], od));
      bool take = (od < bd[i]) || (od == bd[i] && oi < bi[i]);
      bd[i] = take ? od : bd[i];
      bi[i] = take ? oi : bi[i];
      b2[i] = nb2;
    }
  }

  float fit_p = 0.f;
  if (lcol == 0) {
#pragma unroll
    for (int i = 0; i < 8; ++i) {
      int s = i >> 2, ii = i & 3;
      int rloc = wave * 32 + s * 16 + quad * 4 + ii;
      int rowg = row0 + rloc;
      out[XL_OFF + rowg] = (float)bi[i];
      sIdx[rloc] = bi[i];
      fit_p += bd[i] + sx2[rloc];
      if (b2[i] - bd[i] < TAU) {
        int slot = atomicAdd(flag_cnt, 1);
        if (slot < MAXFLAG) flags[slot] = rowg;
      }
    }
  }
  __syncthreads();

  {
    int rr = tid >> 1, half = tid & 1;
    const float4* kr4 = (const float4*)(kg + (size_t)sIdx[rr] * WDIM + half * 32);
    float4* dst = (float4*)&kd[rr * 68 + half * 32];
#pragma unroll
    for (int j = 0; j < 8; ++j) dst[j] = kr4[j];
  }
  __syncthreads();

  float commit_p = 0.f;
  float* xdb = out + XD_OFF + (size_t)n * WDIM * TDIM + t0 + r;
#pragma unroll 8
  for (int i = 0; i < 32; ++i) {
    int w = 2 * i + wh;
    float xvv = xb[(size_t)w * TDIM];
    float kvv = kd[r * 68 + w];
    float df = kvv - xvv;
    commit_p = fmaf(df, df, commit_p);
    xdb[(size_t)w * TDIM] = kvv;
  }

  float v0 = sxp, v1 = x2p, v2 = commit_p, v3 = fit_p;
#pragma unroll
  for (int off = 32; off > 0; off >>= 1) {
    v0 += __shfl_down(v0, off, 64);
    v1 += __shfl_down(v1, off, 64);
    v2 += __shfl_down(v2, off, 64);
    v3 += __shfl_down(v3, off, 64);
  }
  if (lane == 0) {
    atomicAdd(&wsd[0], (double)v0);
    atomicAdd(&wsd[1], (double)v1);
    atomicAdd(&wsd[2], (double)v2);
    atomicAdd(&wsd[3], (double)v3);
  }
}

// recheck pass 1: np-bit-exact scan. block = (flagged row, 256-code segment);
// one code per thread (single FMA chain -> loads pipeline); wave-min then
// one 64-bit atomicMin per wave on key = (float_bits(d)<<32)|code.
__launch_bounds__(256, 4)
__global__ void recheck_scan(const float* __restrict__ x,
                             const float* __restrict__ kg,
                             const float* __restrict__ k2g,
                             const int* __restrict__ flag_cnt,
                             const int* __restrict__ flags,
                             u64* __restrict__ slots) {
  const int tid = threadIdx.x;
  int nf = *flag_cnt;
  if (nf > MAXFLAG) nf = MAXFLAG;
  const int fi  = blockIdx.x >> 3;
  const int seg = blockIdx.x & 7;
  if (fi >= nf) return;

  __shared__ float sx[WDIM];
  __shared__ float sx2s;
  const int row = flags[fi];
  const int n = row >> 13;
  const int t = row & (TDIM - 1);
  if (tid < WDIM) sx[tid] = x[(size_t)n * WDIM * TDIM + (size_t)tid * TDIM + t];
  __syncthreads();
  if (tid == 0) {   // np-pairwise x2
    float r8[8];
#pragma unroll
    for (int l = 0; l < 8; ++l) r8[l] = __fmul_rn(sx[l], sx[l]);
    for (int i = 8; i < WDIM; i += 8) {
#pragma unroll
      for (int l = 0; l < 8; ++l)
        r8[l] = __fadd_rn(r8[l], __fmul_rn(sx[i + l], sx[i + l]));
    }
    sx2s = __fadd_rn(__fadd_rn(__fadd_rn(r8[0], r8[1]), __fadd_rn(r8[2], r8[3])),
                     __fadd_rn(__fadd_rn(r8[4], r8[5]), __fadd_rn(r8[6], r8[7])));
  }
  __syncthreads();

  const int j = seg * 256 + tid;
  const float* kr = kg + (size_t)j * WDIM;
  float c = 0.f;
#pragma unroll
  for (int w = 0; w < WDIM; ++w)
    c = __fmaf_rn(sx[w], kr[w], c);
  float d = __fadd_rn(__fsub_rn(sx2s, __fmul_rn(2.0f, c)), k2g[j]);

  u64 key = ((u64)__float_as_uint(d) << 32) | (unsigned int)j;
#pragma unroll
  for (int off = 32; off > 0; off >>= 1) {
    u64 o = __shfl_down((unsigned long long)key, off, 64);
    if (o < key) key = o;
  }
  if ((tid & 63) == 0) atomicMin(&slots[fi], key);
}

// recheck pass 2: write winners back.
__global__ void recheck_write(const float* __restrict__ kg,
                              const int* __restrict__ flag_cnt,
                              const int* __restrict__ flags,
                              const u64* __restrict__ slots,
                              float* __restrict__ out) {
  int nf = *flag_cnt;
  if (nf > MAXFLAG) nf = MAXFLAG;
  const int fi = blockIdx.x;
  if (fi >= nf) return;
  const int row = flags[fi];
  const int n = row >> 13;
  const int t = row & (TDIM - 1);
  const int j = (int)(slots[fi] & 0xFFFFFFFFULL);
  const int w = threadIdx.x;
  if (w == 0) out[XL_OFF + row] = (float)j;
  out[XD_OFF + (size_t)n * WDIM * TDIM + (size_t)w * TDIM + t] = kg[(size_t)j * WDIM + w];
}

__global__ void finalize_kernel(const double* __restrict__ wsd, float* __restrict__ out) {
  if (threadIdx.x == 0) {
    double size = (double)XSIZE;
    double commit = wsd[2] / size;
    double fit = wsd[3] / (double)NROWS;
    double mean = wsd[0] / size;
    double var = wsd[1] / size - mean * mean;
    if (var < 0.0) var = 0.0;
    out[SCAL_OFF + 0] = (float)commit;
    out[SCAL_OFF + 1] = (float)fit;
    out[SCAL_OFF + 2] = (float)sqrt(var);
  }
}

extern "C" void kernel_launch(void* const* d_in, const int* in_sizes, int n_in,
                              void* d_out, int out_size, void* d_ws, size_t ws_size,
                              hipStream_t stream) {
  const float* x = (const float*)d_in[0];
  const float* kg = (const float*)d_in[1];
  float* out = (float*)d_out;
  double* wsd = (double*)d_ws;
  float* k2  = (float*)((char*)d_ws + WS_K2_OFF);
  int* cnt   = (int*)((char*)d_ws + WS_CNT_OFF);
  int* flags = (int*)((char*)d_ws + WS_FLAG_OFF);
  u64* slots = (u64*)((char*)d_ws + WS_SLOT_OFF);
  short* khi = (short*)((char*)d_ws + WS_KHI_OFF);
  short* klo = (short*)((char*)d_ws + WS_KLO_OFF);

  hipLaunchKernelGGL(prep_kernel, dim3(KBINS / 128), dim3(256), 0, stream,
                     kg, k2, khi, klo, wsd, cnt, slots);
  hipLaunchKernelGGL(vq_mfma, dim3(NROWS / MT), dim3(128), 0, stream,
                     x, kg, k2, khi, klo, out, wsd, cnt, flags);
  hipLaunchKernelGGL(recheck_scan, dim3(MAXFLAG * 8), dim3(256), 0, stream,
                     x, kg, k2, cnt, flags, slots);
  hipLaunchKernelGGL(recheck_write, dim3(MAXFLAG), dim3(WDIM), 0, stream,
                     kg, cnt, flags, slots, out);
  hipLaunchKernelGGL(finalize_kernel, dim3(1), dim3(1), 0, stream, wsd, out);
}

// Round 10
// 295.492 us; speedup vs baseline: 4.3904x; 1.1967x over previous
//
#include <hip/hip_runtime.h>
#include <hip/hip_bf16.h>
#include <math.h>

#define N_BATCH 8
#define WDIM 64
#define TDIM 8192
#define KBINS 2048
#define NROWS (N_BATCH * TDIM)          // 65536
#define XSIZE (N_BATCH * WDIM * TDIM)   // 4194304
#define XL_OFF 0
#define XD_OFF NROWS
#define SCAL_OFF (NROWS + XSIZE)

#define MT 64                           // rows per block (vq)
#define XST 72                          // bf16 LDS x row stride
#define TAU 0.05f                       // >=16x worst-case split-bf16 vs np noise
#define MAXFLAG 8192

// ws layout (bytes):
//   0      : double wsd[4]
//   64     : float  k2[KBINS]              (np-bit-exact)
//   8320   : int    flag_cnt
//   8384   : int    flags[MAXFLAG]         (32 KB)
//   41216  : u64    slots[MAXFLAG]         (64 KB)
//   106752 : short  kfrag[KBINS*128]       (512 KB: per 16-code tile, 4 KB =
//            {hi_k0..31, hi_k32..63, lo_k0..31, lo_k32..63} x 64 lanes x 16 B,
//            in exact MFMA B-fragment lane order)
#define WS_K2_OFF   64
#define WS_CNT_OFF  8320
#define WS_FLAG_OFF 8384
#define WS_SLOT_OFF 41216
#define WS_KF_OFF   106752

typedef __attribute__((ext_vector_type(8))) short bf16x8;
typedef __attribute__((ext_vector_type(4))) float f32x4;
typedef unsigned long long u64;

static __device__ __forceinline__ short f2bf(float v) {
  __hip_bfloat16 b = __float2bfloat16(v);
  return *reinterpret_cast<short*>(&b);
}
static __device__ __forceinline__ float bf2f(short s) {
  unsigned int u = ((unsigned int)(unsigned short)s) << 16;
  return __uint_as_float(u);
}

#define GLOAD_LDS(gsrc, ldst)                                            \
  __builtin_amdgcn_global_load_lds(                                      \
      (const __attribute__((address_space(1))) unsigned int*)(gsrc),     \
      (__attribute__((address_space(3))) unsigned int*)(ldst), 16, 0, 0)

// prep: 1 block per 16-code tile. np-bit-exact k2 + fragment-ordered split-bf16
// codebook. Also inits wsd/cnt/slots.
__global__ void prep_kernel(const float* __restrict__ kg, float* __restrict__ k2,
                            short* __restrict__ kfrag,
                            double* __restrict__ wsd, int* __restrict__ cnt,
                            u64* __restrict__ slots) {
  __shared__ float skc[16 * 65];
  const int tid  = threadIdx.x;
  const int tile = blockIdx.x;           // 0..127
  const int c0   = tile * 16;
  if (tile == 0) {
    if (tid < 4) wsd[tid] = 0.0;
    if (tid == 4) *cnt = 0;
  }
  {
    int gid = tile * 256 + tid;
    if (gid < MAXFLAG) slots[gid] = ~0ULL;
  }
  // stage 16 codes (1024 floats) coalesced
  {
    const float4* g4 = (const float4*)(kg + (size_t)c0 * WDIM);
    int code = tid >> 4, w = (tid & 15) * 4;
    *(float4*)&skc[code * 65 + w] = g4[tid];
  }
  __syncthreads();
  if (tid < 16) {   // np-bit-exact k2 (8-accumulator pairwise)
    const float* kr = &skc[tid * 65];
    float r[8];
#pragma unroll
    for (int l = 0; l < 8; ++l) r[l] = __fmul_rn(kr[l], kr[l]);
    for (int i = 8; i < WDIM; i += 8) {
#pragma unroll
      for (int l = 0; l < 8; ++l)
        r[l] = __fadd_rn(r[l], __fmul_rn(kr[i + l], kr[i + l]));
    }
    k2[c0 + tid] = __fadd_rn(__fadd_rn(__fadd_rn(r[0], r[1]), __fadd_rn(r[2], r[3])),
                             __fadd_rn(__fadd_rn(r[4], r[5]), __fadd_rn(r[6], r[7])));
  }
  // fragment store: thread = (sub 0..3, lane 0..63); one 16 B chunk each.
  {
    const int sub  = tid >> 6;
    const int lane = tid & 63;
    const int lcol = lane & 15;
    const int quad = lane >> 4;
    const float* src = &skc[lcol * 65 + (sub & 1) * 32 + quad * 8];
    const bool lo = (sub >= 2);
    short tmp[8];
#pragma unroll
    for (int i = 0; i < 8; ++i) {
      float v = src[i];
      short h = f2bf(v);
      tmp[i] = lo ? f2bf(v - bf2f(h)) : h;
    }
    char* dst = (char*)kfrag + (size_t)tile * 4096 + sub * 1024 + lane * 16;
    *(bf16x8*)dst = *(const bf16x8*)tmp;
  }
}

// main: split-bf16 MFMA scan. B staged via async global_load_lds (fragment
// layout -> contiguous lane*16 ds_read_b128, conflict-free), double-buffered,
// one barrier per 32-code chunk.
__launch_bounds__(128, 2)
__global__ void vq_mfma(const float* __restrict__ x,
                        const float* __restrict__ kg,
                        const float* __restrict__ k2g,
                        const short* __restrict__ kfrag,
                        float* __restrict__ out,
                        double* __restrict__ wsd,
                        int* __restrict__ flag_cnt,
                        int* __restrict__ flags) {
  __shared__ __align__(16) char smem[35840];
  short* sxh  = (short*)smem;              // [64][72] bf16 hi   (9216 B)
  short* sxl  = (short*)(smem + 9216);     // [64][72] bf16 lo   (9216 B)
  char*  kbuf = smem + 18432;              // 2 x 8192 B chunk buffers
  float* sx2  = (float*)(smem + 34816);    // per-row x2         (256 B)
  float* sPair= (float*)(smem + 35072);    // x2 partials        (512 B)
  int*   sIdx = (int*)  (smem + 35584);    // chosen code/row    (256 B)
  float* kd   = (float*)smem;              // epilogue [64][68] f32 (reuses sxh/sxl)

  const int tid  = threadIdx.x;
  const int row0 = blockIdx.x * MT;
  const int n    = row0 >> 13;
  const int t0   = row0 & (TDIM - 1);

  // ---- stage x tile -> split bf16; fp32 partials ----
  const int r  = tid & 63;
  const int wh = tid >> 6;
  float x2p = 0.f, sxp = 0.f;
  const float* xb = x + (size_t)n * WDIM * TDIM + t0 + r;
#pragma unroll 8
  for (int i = 0; i < 32; ++i) {
    int w = 2 * i + wh;
    float v = xb[(size_t)w * TDIM];
    x2p = fmaf(v, v, x2p);
    sxp += v;
    short h = f2bf(v);
    sxh[r * XST + w] = h;
    sxl[r * XST + w] = f2bf(v - bf2f(h));
  }
  sPair[tid] = x2p;
  __syncthreads();
  if (tid < MT) sx2[tid] = sPair[tid] + sPair[tid + 64];
  __syncthreads();

  // ---- A fragments (registers for the whole sweep) ----
  const int wave = tid >> 6;
  const int lane = tid & 63;
  const int lcol = lane & 15;
  const int quad = lane >> 4;
  const int rA0 = wave * 32 + lcol;
  const int rA1 = wave * 32 + 16 + lcol;
  bf16x8 a0h0 = *(const bf16x8*)&sxh[rA0 * XST + 0  + quad * 8];
  bf16x8 a0h1 = *(const bf16x8*)&sxh[rA0 * XST + 32 + quad * 8];
  bf16x8 a0l0 = *(const bf16x8*)&sxl[rA0 * XST + 0  + quad * 8];
  bf16x8 a0l1 = *(const bf16x8*)&sxl[rA0 * XST + 32 + quad * 8];
  bf16x8 a1h0 = *(const bf16x8*)&sxh[rA1 * XST + 0  + quad * 8];
  bf16x8 a1h1 = *(const bf16x8*)&sxh[rA1 * XST + 32 + quad * 8];
  bf16x8 a1l0 = *(const bf16x8*)&sxl[rA1 * XST + 0  + quad * 8];
  bf16x8 a1l1 = *(const bf16x8*)&sxl[rA1 * XST + 32 + quad * 8];

  float bd[8], b2[8];
  int   bi[8];
#pragma unroll
  for (int i = 0; i < 8; ++i) { bd[i] = 3.0e38f; b2[i] = 3.0e38f; bi[i] = 0; }

  const char* kfg = (const char*)kfrag;

#define VQ_STEP(BH0, BH1, BL0, BL1, KK, CB)                                  \
  {                                                                          \
    f32x4 acc0 = {0.f, 0.f, 0.f, 0.f};                                       \
    f32x4 acc1 = {0.f, 0.f, 0.f, 0.f};                                       \
    acc0 = __builtin_amdgcn_mfma_f32_16x16x32_bf16(a0h0, BH0, acc0, 0, 0, 0);\
    acc1 = __builtin_amdgcn_mfma_f32_16x16x32_bf16(a1h0, BH0, acc1, 0, 0, 0);\
    acc0 = __builtin_amdgcn_mfma_f32_16x16x32_bf16(a0h1, BH1, acc0, 0, 0, 0);\
    acc1 = __builtin_amdgcn_mfma_f32_16x16x32_bf16(a1h1, BH1, acc1, 0, 0, 0);\
    acc0 = __builtin_amdgcn_mfma_f32_16x16x32_bf16(a0h0, BL0, acc0, 0, 0, 0);\
    acc1 = __builtin_amdgcn_mfma_f32_16x16x32_bf16(a1h0, BL0, acc1, 0, 0, 0);\
    acc0 = __builtin_amdgcn_mfma_f32_16x16x32_bf16(a0h1, BL1, acc0, 0, 0, 0);\
    acc1 = __builtin_amdgcn_mfma_f32_16x16x32_bf16(a1h1, BL1, acc1, 0, 0, 0);\
    acc0 = __builtin_amdgcn_mfma_f32_16x16x32_bf16(a0l0, BH0, acc0, 0, 0, 0);\
    acc1 = __builtin_amdgcn_mfma_f32_16x16x32_bf16(a1l0, BH0, acc1, 0, 0, 0);\
    acc0 = __builtin_amdgcn_mfma_f32_16x16x32_bf16(a0l1, BH1, acc0, 0, 0, 0);\
    acc1 = __builtin_amdgcn_mfma_f32_16x16x32_bf16(a1l1, BH1, acc1, 0, 0, 0);\
    const int code = (CB) + lcol;                                            \
    _Pragma("unroll")                                                        \
    for (int i = 0; i < 4; ++i) {                                            \
      float d0 = fmaf(-2.f, acc0[i], KK);                                    \
      float nb2a = fminf(b2[i], fmaxf(bd[i], d0));                           \
      bool lt0 = d0 < bd[i];                                                 \
      bd[i] = lt0 ? d0 : bd[i];                                              \
      bi[i] = lt0 ? code : bi[i];                                            \
      b2[i] = nb2a;                                                          \
      float d1 = fmaf(-2.f, acc1[i], KK);                                    \
      float nb2b = fminf(b2[4 + i], fmaxf(bd[4 + i], d1));                   \
      bool lt1 = d1 < bd[4 + i];                                             \
      bd[4 + i] = lt1 ? d1 : bd[4 + i];                                      \
      bi[4 + i] = lt1 ? code : bi[4 + i];                                    \
      b2[4 + i] = nb2b;                                                      \
    }                                                                        \
  }

  // async prefetch of chunk c into buffer b (each wave stages 4 KB)
#define VQ_ISSUE(C, B)                                                       \
  {                                                                          \
    const char* s = kfg + (size_t)(C) * 8192 + wave * 4096 + (lane << 4);    \
    char* d = kbuf + (B) * 8192 + wave * 4096;                               \
    GLOAD_LDS(s, d);                                                         \
    GLOAD_LDS(s + 1024, d + 1024);                                           \
    GLOAD_LDS(s + 2048, d + 2048);                                           \
    GLOAD_LDS(s + 3072, d + 3072);                                           \
  }

  VQ_ISSUE(0, 0)
  __syncthreads();
  for (int c = 0; c < KBINS / 32; ++c) {
    const int buf = c & 1;
    if (c + 1 < KBINS / 32) VQ_ISSUE(c + 1, buf ^ 1)
    const char* tb0 = kbuf + buf * 8192;
    const char* tb1 = tb0 + 4096;
    bf16x8 bh0 = *(const bf16x8*)(tb0 + 0    + (lane << 4));
    bf16x8 bh1 = *(const bf16x8*)(tb0 + 1024 + (lane << 4));
    bf16x8 bl0 = *(const bf16x8*)(tb0 + 2048 + (lane << 4));
    bf16x8 bl1 = *(const bf16x8*)(tb0 + 3072 + (lane << 4));
    float k2c0 = k2g[c * 32 + lcol];
    VQ_STEP(bh0, bh1, bl0, bl1, k2c0, c * 32)
    bf16x8 ch0 = *(const bf16x8*)(tb1 + 0    + (lane << 4));
    bf16x8 ch1 = *(const bf16x8*)(tb1 + 1024 + (lane << 4));
    bf16x8 cl0 = *(const bf16x8*)(tb1 + 2048 + (lane << 4));
    bf16x8 cl1 = *(const bf16x8*)(tb1 + 3072 + (lane << 4));
    float k2c1 = k2g[c * 32 + 16 + lcol];
    VQ_STEP(ch0, ch1, cl0, cl1, k2c1, c * 32 + 16)
    __syncthreads();
  }
#undef VQ_STEP
#undef VQ_ISSUE

  // ---- reduce across the 16 col-classes ----
#pragma unroll
  for (int m = 1; m < 16; m <<= 1) {
#pragma unroll
    for (int i = 0; i < 8; ++i) {
      float od  = __shfl_xor(bd[i], m, 64);
      float od2 = __shfl_xor(b2[i], m, 64);
      int   oi  = __shfl_xor(bi[i], m, 64);
      float nb2 = fminf(fminf(b2[i], od2), fmaxf(bd[i], od));
      bool take = (od < bd[i]) || (od == bd[i] && oi < bi[i]);
      bd[i] = take ? od : bd[i];
      bi[i] = take ? oi : bi[i];
      b2[i] = nb2;
    }
  }

  float fit_p = 0.f;
  if (lcol == 0) {
#pragma unroll
    for (int i = 0; i < 8; ++i) {
      int s = i >> 2, ii = i & 3;
      int rloc = wave * 32 + s * 16 + quad * 4 + ii;
      int rowg = row0 + rloc;
      out[XL_OFF + rowg] = (float)bi[i];
      sIdx[rloc] = bi[i];
      fit_p += bd[i] + sx2[rloc];
      if (b2[i] - bd[i] < TAU) {
        int slot = atomicAdd(flag_cnt, 1);
        if (slot < MAXFLAG) flags[slot] = rowg;
      }
    }
  }
  __syncthreads();

  // ---- gather chosen code rows (fp32) into LDS ----
  {
    int rr = tid >> 1, half = tid & 1;
    const float4* kr4 = (const float4*)(kg + (size_t)sIdx[rr] * WDIM + half * 32);
    float4* dst = (float4*)&kd[rr * 68 + half * 32];
#pragma unroll
    for (int j = 0; j < 8; ++j) dst[j] = kr4[j];
  }
  __syncthreads();

  // ---- x_d transposed write + commit ----
  float commit_p = 0.f;
  float* xdb = out + XD_OFF + (size_t)n * WDIM * TDIM + t0 + r;
#pragma unroll 8
  for (int i = 0; i < 32; ++i) {
    int w = 2 * i + wh;
    float xvv = xb[(size_t)w * TDIM];
    float kvv = kd[r * 68 + w];
    float df = kvv - xvv;
    commit_p = fmaf(df, df, commit_p);
    xdb[(size_t)w * TDIM] = kvv;
  }

  float v0 = sxp, v1 = x2p, v2 = commit_p, v3 = fit_p;
#pragma unroll
  for (int off = 32; off > 0; off >>= 1) {
    v0 += __shfl_down(v0, off, 64);
    v1 += __shfl_down(v1, off, 64);
    v2 += __shfl_down(v2, off, 64);
    v3 += __shfl_down(v3, off, 64);
  }
  if (lane == 0) {
    atomicAdd(&wsd[0], (double)v0);
    atomicAdd(&wsd[1], (double)v1);
    atomicAdd(&wsd[2], (double)v2);
    atomicAdd(&wsd[3], (double)v3);
  }
}

// recheck pass 1: persistent grid; item = (flagged row, 256-code segment).
__launch_bounds__(256, 4)
__global__ void recheck_scan(const float* __restrict__ x,
                             const float* __restrict__ kg,
                             const float* __restrict__ k2g,
                             const int* __restrict__ flag_cnt,
                             const int* __restrict__ flags,
                             u64* __restrict__ slots) {
  __shared__ float sx[WDIM];
  __shared__ float sx2s;
  const int tid = threadIdx.x;
  int nf = *flag_cnt;
  if (nf > MAXFLAG) nf = MAXFLAG;
  const int total = nf * 8;

  for (int g = blockIdx.x; g < total; g += 2048) {
    const int fi  = g >> 3;
    const int seg = g & 7;
    const int row = flags[fi];
    const int n = row >> 13;
    const int t = row & (TDIM - 1);
    if (tid < WDIM) sx[tid] = x[(size_t)n * WDIM * TDIM + (size_t)tid * TDIM + t];
    __syncthreads();
    if (tid == 0) {   // np-pairwise x2
      float r8[8];
#pragma unroll
      for (int l = 0; l < 8; ++l) r8[l] = __fmul_rn(sx[l], sx[l]);
      for (int i = 8; i < WDIM; i += 8) {
#pragma unroll
        for (int l = 0; l < 8; ++l)
          r8[l] = __fadd_rn(r8[l], __fmul_rn(sx[i + l], sx[i + l]));
      }
      sx2s = __fadd_rn(__fadd_rn(__fadd_rn(r8[0], r8[1]), __fadd_rn(r8[2], r8[3])),
                       __fadd_rn(__fadd_rn(r8[4], r8[5]), __fadd_rn(r8[6], r8[7])));
    }
    __syncthreads();

    const int j = seg * 256 + tid;
    const float* kr = kg + (size_t)j * WDIM;
    float c = 0.f;
#pragma unroll
    for (int w = 0; w < WDIM; ++w)
      c = __fmaf_rn(sx[w], kr[w], c);
    float d = __fadd_rn(__fsub_rn(sx2s, __fmul_rn(2.0f, c)), k2g[j]);

    u64 key = ((u64)__float_as_uint(d) << 32) | (unsigned int)j;
#pragma unroll
    for (int off = 32; off > 0; off >>= 1) {
      u64 o = __shfl_down((unsigned long long)key, off, 64);
      if (o < key) key = o;
    }
    if ((tid & 63) == 0) atomicMin(&slots[fi], key);
    __syncthreads();
  }
}

// recheck pass 2: persistent write-back.
__global__ void recheck_write(const float* __restrict__ kg,
                              const int* __restrict__ flag_cnt,
                              const int* __restrict__ flags,
                              const u64* __restrict__ slots,
                              float* __restrict__ out) {
  int nf = *flag_cnt;
  if (nf > MAXFLAG) nf = MAXFLAG;
  const int w = threadIdx.x;
  for (int fi = blockIdx.x; fi < nf; fi += 256) {
    const int row = flags[fi];
    const int n = row >> 13;
    const int t = row & (TDIM - 1);
    const int j = (int)(slots[fi] & 0xFFFFFFFFULL);
    if (w == 0) out[XL_OFF + row] = (float)j;
    out[XD_OFF + (size_t)n * WDIM * TDIM + (size_t)w * TDIM + t] = kg[(size_t)j * WDIM + w];
  }
}

__global__ void finalize_kernel(const double* __restrict__ wsd, float* __restrict__ out) {
  if (threadIdx.x == 0) {
    double size = (double)XSIZE;
    double commit = wsd[2] / size;
    double fit = wsd[3] / (double)NROWS;
    double mean = wsd[0] / size;
    double var = wsd[1] / size - mean * mean;
    if (var < 0.0) var = 0.0;
    out[SCAL_OFF + 0] = (float)commit;
    out[SCAL_OFF + 1] = (float)fit;
    out[SCAL_OFF + 2] = (float)sqrt(var);
  }
}

extern "C" void kernel_launch(void* const* d_in, const int* in_sizes, int n_in,
                              void* d_out, int out_size, void* d_ws, size_t ws_size,
                              hipStream_t stream) {
  const float* x = (const float*)d_in[0];
  const float* kg = (const float*)d_in[1];
  float* out = (float*)d_out;
  double* wsd = (double*)d_ws;
  float* k2   = (float*)((char*)d_ws + WS_K2_OFF);
  int* cnt    = (int*)((char*)d_ws + WS_CNT_OFF);
  int* flags  = (int*)((char*)d_ws + WS_FLAG_OFF);
  u64* slots  = (u64*)((char*)d_ws + WS_SLOT_OFF);
  short* kfrag= (short*)((char*)d_ws + WS_KF_OFF);

  hipLaunchKernelGGL(prep_kernel, dim3(KBINS / 16), dim3(256), 0, stream,
                     kg, k2, kfrag, wsd, cnt, slots);
  hipLaunchKernelGGL(vq_mfma, dim3(NROWS / MT), dim3(128), 0, stream,
                     x, kg, k2, kfrag, out, wsd, cnt, flags);
  hipLaunchKernelGGL(recheck_scan, dim3(2048), dim3(256), 0, stream,
                     x, kg, k2, cnt, flags, slots);
  hipLaunchKernelGGL(recheck_write, dim3(256), dim3(WDIM), 0, stream,
                     kg, cnt, flags, slots, out);
  hipLaunchKernelGGL(finalize_kernel, dim3(1), dim3(1), 0, stream, wsd, out);
}